// Round 2
// baseline (903.148 us; speedup 1.0000x reference)
//
#include <hip/hip_runtime.h>

#define H_DIM 1024
#define B_DIM 128
#define S_DIM 256
#define V_DIM 32000
#define E_DIM 512

typedef __bf16 bf16_t;
typedef bf16_t bf16x8 __attribute__((ext_vector_type(8)));
typedef bf16_t bf16x4 __attribute__((ext_vector_type(4)));
typedef float floatx4 __attribute__((ext_vector_type(4)));

#define BM 128
#define BN 128
#define BK 64
#define LDK (BK + 8)

__device__ inline float fast_tanh(float x) {
    x = fminf(fmaxf(x, -15.f), 15.f);
    float e = __expf(2.f * x);
    return (e - 1.f) / (e + 1.f);
}
__device__ inline float sigmoidf_(float x) { return 1.f / (1.f + __expf(-x)); }
__device__ inline bf16x4 cvt4(float4 v) {
    return (bf16x4){(bf16_t)v.x, (bf16_t)v.y, (bf16_t)v.z, (bf16_t)v.w};
}
__device__ __forceinline__ void gload16(const bf16_t* g, bf16_t* l) {
    __builtin_amdgcn_global_load_lds(
        (const __attribute__((address_space(1))) void*)g,
        (__attribute__((address_space(3))) void*)l, 16, 0, 0);
}

// ---------------- fused prep kernel (pathA) ----------------
// blocks [0,128):   b = blockIdx.x
//    - zero scores[b*256 .. +255]
//    - proj[b][n] = dot(h_top[b], W2[n]) + W2b[n]   (wave-per-row GEMV)
// blocks [128, 2176): grid-stride float4 conversion + packing:
//    - enc fp32 -> encbf bf16      (8388608 f4)
//    - W1  fp32 -> W1bf bf16       (262144 f4)
//    - x0[b][0..511]    = embt[tok[b]]          (16384 f4)
//    - x0[b][1536..2559] = hidden[0][b]          (32768 f4)
//    - x1[b][1024..2047] = hidden[1][b]          (32768 f4)
__global__ __launch_bounds__(256) void prep_kernel(
    const float* __restrict__ enc, bf16_t* __restrict__ encbf,
    const float* __restrict__ W1w, bf16_t* __restrict__ W1bf,
    const int* __restrict__ tok, const float* __restrict__ embt,
    const float* __restrict__ hidden,
    float* __restrict__ x0, float* __restrict__ x1,
    const float* __restrict__ W2w, const float* __restrict__ W2b,
    float* __restrict__ proj, float* __restrict__ scores)
{
    const int t = threadIdx.x;
    if (blockIdx.x < 128) {
        const int b = blockIdx.x;
        scores[b * 256 + t] = 0.f;
        const float* h = hidden + (size_t)B_DIM * H_DIM + (size_t)b * H_DIM;
        const int wv = t >> 6, ln = t & 63;
        float4 hr[4];
#pragma unroll
        for (int c = 0; c < 4; c++)
            hr[c] = *(const float4*)(h + c * 256 + ln * 4);
        for (int n = wv; n < H_DIM; n += 4) {
            const float* wrow = W2w + (size_t)n * H_DIM;
            float s = 0.f;
#pragma unroll
            for (int c = 0; c < 4; c++) {
                float4 w4 = *(const float4*)(wrow + c * 256 + ln * 4);
                s += w4.x * hr[c].x + w4.y * hr[c].y + w4.z * hr[c].z + w4.w * hr[c].w;
            }
#pragma unroll
            for (int off = 1; off < 64; off <<= 1) s += __shfl_xor(s, off, 64);
            if (ln == 0) proj[(size_t)b * H_DIM + n] = s + W2b[n];
        }
        return;
    }
    const long long N_ENC = 8388608, N_W1 = 262144, N_EMB = 16384, N_H0 = 32768, N_H1 = 32768;
    const long long total = N_ENC + N_W1 + N_EMB + N_H0 + N_H1;
    const long long stride = (long long)(gridDim.x - 128) * 256;
    for (long long i = (long long)(blockIdx.x - 128) * 256 + t; i < total; i += stride) {
        if (i < N_ENC) {
            float4 v = ((const float4*)enc)[i];
            ((bf16x4*)encbf)[i] = cvt4(v);
        } else if (i < N_ENC + N_W1) {
            long long k = i - N_ENC;
            ((bf16x4*)W1bf)[k] = cvt4(((const float4*)W1w)[k]);
        } else if (i < N_ENC + N_W1 + N_EMB) {
            long long k = i - N_ENC - N_W1;
            int b = (int)(k >> 7), j = (int)(k & 127);
            ((float4*)(x0 + (size_t)b * 2560))[j] =
                ((const float4*)(embt + (size_t)tok[b] * E_DIM))[j];
        } else if (i < N_ENC + N_W1 + N_EMB + N_H0) {
            long long k = i - N_ENC - N_W1 - N_EMB;
            int b = (int)(k >> 8), j = (int)(k & 255);
            ((float4*)(x0 + (size_t)b * 2560 + 1536))[j] =
                ((const float4*)(hidden + (size_t)b * H_DIM))[j];
        } else {
            long long k = i - N_ENC - N_W1 - N_EMB - N_H0;
            int b = (int)(k >> 8), j = (int)(k & 255);
            ((float4*)(x1 + (size_t)b * 2048 + 1024))[j] =
                ((const float4*)(hidden + (size_t)B_DIM * H_DIM + (size_t)b * H_DIM))[j];
        }
    }
}

// ---------------- bf16-input scores GEMM (Path A) ----------------
// scores[m] += sum_n tanh( (A@B^T)[m][n] + bias1[n] + proj[m>>8][n] ) * Vw[n]
// XCD-chunked bijective swizzle retained (keeps A-slices L2/L3-local).
__global__ __launch_bounds__(256) void gemm_scores_bf16(
    const bf16_t* __restrict__ A, const bf16_t* __restrict__ B,
    const float* __restrict__ bias1, const float* __restrict__ proj,
    const float* __restrict__ Vw, float* __restrict__ scores)
{
    __shared__ bf16_t As[128 * 64];
    __shared__ bf16_t Bs[128 * 64];

    const int tid  = threadIdx.x;
    const int wid  = tid >> 6;
    const int lane = tid & 63;

    const int orig = blockIdx.y * gridDim.x + blockIdx.x;   // gridDim = (8,256)
    const int cpx  = (gridDim.x * gridDim.y) >> 3;
    const int wg   = (orig & 7) * cpx + (orig >> 3);
    const int m0 = (wg >> 3) * BM;
    const int n0 = (wg & 7) * BN;

    const int wave_m = (wid & 1) * 64;
    const int wave_n = (wid >> 1) * 64;
    const int laneM  = lane & 15;
    const int laneG  = lane >> 4;

    const int srow = lane >> 3;
    const int pc   = lane & 7;

    floatx4 acc[4][4];
#pragma unroll
    for (int i = 0; i < 4; i++)
#pragma unroll
        for (int j = 0; j < 4; j++) acc[i][j] = (floatx4)0.f;

    for (int k0 = 0; k0 < H_DIM; k0 += BK) {
#pragma unroll
        for (int i = 0; i < 4; i++) {
            int r  = wid * 32 + i * 8 + srow;
            int lc = pc ^ (r & 7);
            gload16(A + (size_t)(m0 + r) * H_DIM + k0 + lc * 8,
                    As + (wid * 32 + i * 8) * 64);
        }
#pragma unroll
        for (int i = 0; i < 4; i++) {
            int r  = wid * 32 + i * 8 + srow;
            int lc = pc ^ (r & 7);
            gload16(B + (size_t)(n0 + r) * H_DIM + k0 + lc * 8,
                    Bs + (wid * 32 + i * 8) * 64);
        }
        __syncthreads();

#pragma unroll
        for (int kk = 0; kk < 2; kk++) {
            bf16x8 af[4], bfb[4];
#pragma unroll
            for (int mt = 0; mt < 4; mt++) {
                int ra = wave_m + mt * 16 + laneM;
                int pa = (kk * 4 + laneG) ^ (ra & 7);
                af[mt] = *(const bf16x8*)(&As[ra * 64 + pa * 8]);
            }
#pragma unroll
            for (int nt = 0; nt < 4; nt++) {
                int rb = wave_n + nt * 16 + laneM;
                int pb = (kk * 4 + laneG) ^ (rb & 7);
                bfb[nt] = *(const bf16x8*)(&Bs[rb * 64 + pb * 8]);
            }
#pragma unroll
            for (int mt = 0; mt < 4; mt++)
#pragma unroll
                for (int nt = 0; nt < 4; nt++)
                    acc[mt][nt] = __builtin_amdgcn_mfma_f32_16x16x32_bf16(
                        af[mt], bfb[nt], acc[mt][nt], 0, 0, 0);
        }
        __syncthreads();
    }

#pragma unroll
    for (int mt = 0; mt < 4; mt++) {
#pragma unroll
        for (int r = 0; r < 4; r++) {
            int m = m0 + wave_m + mt * 16 + (lane >> 4) * 4 + r;
            int b = m >> 8;
            float v = 0.f;
#pragma unroll
            for (int nt = 0; nt < 4; nt++) {
                int n = n0 + wave_n + nt * 16 + laneM;
                float t = acc[mt][nt][r] + bias1[n] + proj[(size_t)b * H_DIM + n];
                v += fast_tanh(t) * Vw[n];
            }
#pragma unroll
            for (int off = 1; off < 16; off <<= 1) v += __shfl_xor(v, off, 64);
            if (laneM == 0) atomicAdd(&scores[m], v);
        }
    }
}

// ---------------- fp32-input GEMM with register-prefetch pipeline ----------------
template <int MODE>
__global__ __launch_bounds__(256) void gemm2(
    const float* __restrict__ A, int lda,
    const float* __restrict__ B1, int ldb1,
    const float* __restrict__ B2, int ldb2, int splitB,
    int K, int kChunk,
    float* __restrict__ C, int ldc,
    float* __restrict__ Cpart, long long partStride,
    const float* __restrict__ bias1, const float* __restrict__ bias2,
    const float* __restrict__ proj, const float* __restrict__ Vw,
    float* __restrict__ scores)
{
    __shared__ bf16_t As[BM][LDK];
    __shared__ bf16_t Bs[BN][LDK];

    const int tid  = threadIdx.x;
    const int wid  = tid >> 6;
    const int lane = tid & 63;

    int bx = blockIdx.x, by = blockIdx.y;
    if (MODE == 1) {
        int nwg  = gridDim.x * gridDim.y;
        int orig = by * gridDim.x + bx;
        int cpx  = nwg >> 3;
        int wg   = (orig & 7) * cpx + (orig >> 3);
        bx = wg % gridDim.x;
        by = wg / gridDim.x;
    }
    const int m0 = by * BM;
    const int n0 = bx * BN;

    const int wave_m = (wid & 1) * 64;
    const int wave_n = (wid >> 1) * 64;
    const int laneM  = lane & 15;
    const int laneK  = (lane >> 4) * 8;

    const int tk = (tid & 15) * 4;
    const int tr = tid >> 4;

    const int kStart = blockIdx.z * kChunk;
    const int kEnd   = min(K, kStart + kChunk);

    floatx4 acc[4][4];
#pragma unroll
    for (int i = 0; i < 4; i++)
#pragma unroll
        for (int j = 0; j < 4; j++) acc[i][j] = (floatx4)0.f;

    const float* Arow = A + (size_t)(m0 + tr) * lda + tk;

    float4 ar[8], br[8];
    auto loadA = [&](int k0) {
#pragma unroll
        for (int p = 0; p < 8; p++)
            ar[p] = *(const float4*)(Arow + (size_t)(p * 16) * lda + k0);
    };
    auto loadB = [&](int k0) {
        const float* Bp; size_t ldb; int kb;
        if (k0 < splitB) { Bp = B1; ldb = (size_t)ldb1; kb = k0 + tk; }
        else             { Bp = B2; ldb = (size_t)ldb2; kb = k0 - splitB + tk; }
        const float* Brow = Bp + (size_t)(n0 + tr) * ldb + kb;
#pragma unroll
        for (int p = 0; p < 8; p++)
            br[p] = *(const float4*)(Brow + (size_t)(p * 16) * ldb);
    };

    loadA(kStart); loadB(kStart);

    for (int k0 = kStart; k0 < kEnd; k0 += BK) {
#pragma unroll
        for (int p = 0; p < 8; p++) *(bf16x4*)(&As[tr + p * 16][tk]) = cvt4(ar[p]);
#pragma unroll
        for (int p = 0; p < 8; p++) *(bf16x4*)(&Bs[tr + p * 16][tk]) = cvt4(br[p]);
        __syncthreads();
        if (k0 + BK < kEnd) { loadA(k0 + BK); loadB(k0 + BK); }
#pragma unroll
        for (int kk = 0; kk < 2; kk++) {
            bf16x8 af[4], bfb[4];
#pragma unroll
            for (int mt = 0; mt < 4; mt++)
                af[mt] = *(const bf16x8*)(&As[wave_m + mt * 16 + laneM][kk * 32 + laneK]);
#pragma unroll
            for (int nt = 0; nt < 4; nt++)
                bfb[nt] = *(const bf16x8*)(&Bs[wave_n + nt * 16 + laneM][kk * 32 + laneK]);
#pragma unroll
            for (int mt = 0; mt < 4; mt++)
#pragma unroll
                for (int nt = 0; nt < 4; nt++)
                    acc[mt][nt] = __builtin_amdgcn_mfma_f32_16x16x32_bf16(
                        af[mt], bfb[nt], acc[mt][nt], 0, 0, 0);
        }
        __syncthreads();
    }

    if (MODE == 2 || MODE == 3) {
        const bool addb = (blockIdx.z == 0);
        float* dst = C;
        if (MODE == 3 && blockIdx.z > 0)
            dst = Cpart + (size_t)(blockIdx.z - 1) * partStride;
#pragma unroll
        for (int mt = 0; mt < 4; mt++) {
            int mrow = m0 + wave_m + mt * 16 + (lane >> 4) * 4;
#pragma unroll
            for (int nt = 0; nt < 4; nt++) {
                int n = n0 + wave_n + nt * 16 + laneM;
                float bsum = 0.f;
                if (addb) bsum = (bias1 ? bias1[n] : 0.f) + (bias2 ? bias2[n] : 0.f);
#pragma unroll
                for (int r = 0; r < 4; r++) {
                    float val = acc[mt][nt][r] + bsum;
                    if (MODE == 2) atomicAdd(&C[(size_t)(mrow + r) * ldc + n], val);
                    else           dst[(size_t)(mrow + r) * ldc + n] = val;
                }
            }
        }
    } else {  // MODE 1
#pragma unroll
        for (int mt = 0; mt < 4; mt++) {
#pragma unroll
            for (int r = 0; r < 4; r++) {
                int m = m0 + wave_m + mt * 16 + (lane >> 4) * 4 + r;
                int b = m >> 8;
                float v = 0.f;
#pragma unroll
                for (int nt = 0; nt < 4; nt++) {
                    int n = n0 + wave_n + nt * 16 + laneM;
                    float t = acc[mt][nt][r] + bias1[n] + proj[(size_t)b * H_DIM + n];
                    v += fast_tanh(t) * Vw[n];
                }
#pragma unroll
                for (int off = 1; off < 16; off <<= 1) v += __shfl_xor(v, off, 64);
                if (laneM == 0) atomicAdd(&scores[m], v);
            }
        }
    }
}

__global__ void convert_kernel(const float* __restrict__ src,
                               bf16_t* __restrict__ dst, int n4) {
    int i = blockIdx.x * blockDim.x + threadIdx.x;
    int stride = gridDim.x * blockDim.x;
    for (; i < n4; i += stride) {
        float4 v = ((const float4*)src)[i];
        ((bf16x4*)dst)[i] = cvt4(v);
    }
}

// fused softmax over scores + context reduce; grid (B, 2), 2 cols/thread
template <typename T>
__global__ __launch_bounds__(256) void softmax_context_kernel(
    const T* __restrict__ enc, const float* __restrict__ scores,
    float* __restrict__ out_attn, float* __restrict__ x0, float* __restrict__ x2)
{
    __shared__ float red[256];
    __shared__ float a_s[256];
    int b = blockIdx.x, t = threadIdx.x;
    int half = blockIdx.y;
    float v = scores[b * S_DIM + t];
    red[t] = v; __syncthreads();
    for (int off = 128; off > 0; off >>= 1) {
        if (t < off) red[t] = fmaxf(red[t], red[t + off]);
        __syncthreads();
    }
    float mx = red[0]; __syncthreads();
    float e = __expf(v - mx);
    red[t] = e; __syncthreads();
    for (int off = 128; off > 0; off >>= 1) {
        if (t < off) red[t] += red[t + off];
        __syncthreads();
    }
    float a = e / red[0];
    if (half == 0) out_attn[b * S_DIM + t] = a;
    a_s[t] = a;
    __syncthreads();

    const int col = half * 512 + 2 * t;
    const T* base = enc + (size_t)b * S_DIM * H_DIM + col;
    float c0 = 0.f, c1 = 0.f;
#pragma unroll 4
    for (int s = 0; s < S_DIM; s++) {
        float aw = a_s[s];
        const T* row = base + (size_t)s * H_DIM;
        c0 += aw * (float)row[0];
        c1 += aw * (float)row[1];
    }
    x0[(size_t)b * 2560 + 512 + col]      = c0;
    x0[(size_t)b * 2560 + 512 + col + 1]  = c1;
    x2[(size_t)b * 2048 + 1024 + col]     = c0;
    x2[(size_t)b * 2048 + 1024 + col + 1] = c1;
}

__global__ void pack_misc_kernel(const int* __restrict__ tok,
                                 const float* __restrict__ emb_table,
                                 const float* __restrict__ hidden,
                                 float* __restrict__ x0, float* __restrict__ x1) {
    int b = blockIdx.y;
    int k = blockIdx.x * 256 + threadIdx.x;
    if (k < E_DIM)
        x0[(size_t)b * 2560 + k] = emb_table[(size_t)tok[b] * E_DIM + k];
    else if (k < E_DIM + H_DIM)
        x0[(size_t)b * 2560 + 1024 + k] = hidden[b * H_DIM + (k - E_DIM)];
    else
        x1[(size_t)b * 2048 + 1024 + (k - E_DIM - H_DIM)] =
            hidden[(size_t)B_DIM * H_DIM + b * H_DIM + (k - E_DIM - H_DIM)];
}

__global__ void lstm_cell_kernel(const float* __restrict__ gates,
                                 const float* __restrict__ gpart, int nExtra,
                                 long long partStride,
                                 const float* __restrict__ c_in,
                                 float* __restrict__ hx, int hx_stride,
                                 float* __restrict__ h_out,
                                 float* __restrict__ c_out) {
    int b = blockIdx.y;
    int n = blockIdx.x * 256 + threadIdx.x;
    size_t base = (size_t)b * 4 * H_DIM;
    float gi = gates[base + n];
    float gf = gates[base + H_DIM + n];
    float gg = gates[base + 2 * H_DIM + n];
    float go = gates[base + 3 * H_DIM + n];
    for (int p = 0; p < nExtra; p++) {
        size_t pb = (size_t)p * partStride + base;
        gi += gpart[pb + n];
        gf += gpart[pb + H_DIM + n];
        gg += gpart[pb + 2 * H_DIM + n];
        go += gpart[pb + 3 * H_DIM + n];
    }
    float i = sigmoidf_(gi), f = sigmoidf_(gf), o = sigmoidf_(go);
    float g = fast_tanh(gg);
    float c = f * c_in[b * H_DIM + n] + i * g;
    float h = o * fast_tanh(c);
    hx[(size_t)b * hx_stride + n] = h;
    h_out[b * H_DIM + n] = h;
    c_out[b * H_DIM + n] = c;
}

__global__ __launch_bounds__(1024) void log_softmax_kernel(
    float* __restrict__ pred, const float* __restrict__ part) {
    __shared__ float red[1024];
    int b = blockIdx.x, t = threadIdx.x;
    float lv[32];
    float mx = -1e30f;
#pragma unroll
    for (int j = 0; j < 32; j++) {
        int v = t + j * 1024;
        float x = -1e30f;
        if (v < V_DIM) {
            x = pred[(size_t)b * V_DIM + v];
            if (part) x += part[(size_t)b * V_DIM + v];
        }
        lv[j] = x;
        mx = fmaxf(mx, x);
    }
    red[t] = mx; __syncthreads();
    for (int off = 512; off > 0; off >>= 1) {
        if (t < off) red[t] = fmaxf(red[t], red[t + off]);
        __syncthreads();
    }
    mx = red[0]; __syncthreads();
    float s = 0.f;
#pragma unroll
    for (int j = 0; j < 32; j++) s += __expf(lv[j] - mx);
    red[t] = s; __syncthreads();
    for (int off = 512; off > 0; off >>= 1) {
        if (t < off) red[t] += red[t + off];
        __syncthreads();
    }
    float lse = mx + __logf(red[0]);
#pragma unroll
    for (int j = 0; j < 32; j++) {
        int v = t + j * 1024;
        if (v < V_DIM) pred[(size_t)b * V_DIM + v] = lv[j] - lse;
    }
}

extern "C" void kernel_launch(void* const* d_in, const int* in_sizes, int n_in,
                              void* d_out, int out_size, void* d_ws, size_t ws_size,
                              hipStream_t stream) {
    const int*   tok    = (const int*)  d_in[0];
    const float* hidden = (const float*)d_in[1];
    const float* cell   = (const float*)d_in[2];
    const float* enc    = (const float*)d_in[3];
    const float* embt   = (const float*)d_in[4];
    const float* W1w    = (const float*)d_in[5];
    const float* W1b    = (const float*)d_in[6];
    const float* W2w    = (const float*)d_in[7];
    const float* W2b    = (const float*)d_in[8];
    const float* Vw     = (const float*)d_in[9];
    const float* wih0 = (const float*)d_in[11];
    const float* whh0 = (const float*)d_in[12];
    const float* bih0 = (const float*)d_in[13];
    const float* bhh0 = (const float*)d_in[14];
    const float* wih1 = (const float*)d_in[15];
    const float* whh1 = (const float*)d_in[16];
    const float* bih1 = (const float*)d_in[17];
    const float* bhh1 = (const float*)d_in[18];
    const float* fcw  = (const float*)d_in[19];
    const float* fcb  = (const float*)d_in[20];

    float* out        = (float*)d_out;
    float* pred       = out;
    float* out_hidden = out + (size_t)B_DIM * V_DIM;
    float* out_cell   = out_hidden + 2 * B_DIM * H_DIM;
    float* out_attn   = out_cell + 2 * B_DIM * H_DIM;

    // unified ws layout (float offsets)
    float* ws      = (float*)d_ws;
    float* scores  = ws;                      // 32768
    float* proj    = ws + 32768;              // 131072
    float* gatesA  = ws + 163840;             // 524288
    float* gatesB  = ws + 688128;             // 524288
    float* x0      = ws + 1212416;            // 327680
    float* x1      = ws + 1540096;            // 262144
    float* x2      = ws + 1802240;            // 262144
    float* gAp     = ws + 2064384;            // 3*524288   (fallback split path)
    float* gBp     = ws + 3637248;            // 3*524288
    float* fcpart  = ws + 5210112;            // 4096000 (also holds gates z-partials)
    bf16_t* encbf  = (bf16_t*)(ws + 9306112); // 33554432 bf16
    bf16_t* W1bf   = (bf16_t*)(ws + 26083328);// 1048576 bf16

    const bool pathA = ws_size >= (size_t)26607616 * 4;
    const bool pathB = !pathA && ws_size >= (size_t)9306112 * 4 + 16384000;
    const bool split = pathA || pathB;

    dim3 blk(256);

    if (pathA) {
        // fused: memset(scores) + proj GEMV + enc/W1 convert + pack   (1 dispatch)
        prep_kernel<<<dim3(2176), blk, 0, stream>>>(
            enc, encbf, W1w, W1bf, tok, embt, hidden, x0, x1, W2w, W2b, proj, scores);

        gemm_scores_bf16<<<dim3(8, 256), blk, 0, stream>>>(
            encbf, W1bf, W1b, proj, Vw, scores);
        softmax_context_kernel<bf16_t><<<dim3(B_DIM, 2), 256, 0, stream>>>(
            encbf, scores, out_attn, x0, x2);

        // gates0 = x0 @ [wih0|whh0]^T + b  (M=128,N=4096,K=2560), z=8, partials in fcpart
        gemm2<3><<<dim3(32, 1, 8), blk, 0, stream>>>(
            x0, 2560, wih0, 1536, whh0, H_DIM, 1536, 2560, 320,
            gatesA, 4096, fcpart, 524288, bih0, bhh0, nullptr, nullptr, nullptr);
        lstm_cell_kernel<<<dim3(4, B_DIM), blk, 0, stream>>>(
            gatesA, fcpart, 7, 524288, cell, x1, 2048, out_hidden, out_cell);

        // gates1 = x1 @ [wih1|whh1]^T + b  (M=128,N=4096,K=2048), z=8
        gemm2<3><<<dim3(32, 1, 8), blk, 0, stream>>>(
            x1, 2048, wih1, H_DIM, whh1, H_DIM, H_DIM, 2048, 256,
            gatesB, 4096, fcpart, 524288, bih1, bhh1, nullptr, nullptr, nullptr);
        lstm_cell_kernel<<<dim3(4, B_DIM), blk, 0, stream>>>(
            gatesB, fcpart, 7, 524288, cell + (size_t)B_DIM * H_DIM, x2, 2048,
            out_hidden + (size_t)B_DIM * H_DIM, out_cell + (size_t)B_DIM * H_DIM);

        // logits = x2 @ fc_w^T + fc_b  (M=128,N=32000,K=2048), z=2
        gemm2<3><<<dim3(250, 1, 2), blk, 0, stream>>>(
            x2, 2048, fcw, 2048, nullptr, 0, 2048, 2048, 1024,
            pred, V_DIM, fcpart, 4096000, fcb, nullptr, nullptr, nullptr, nullptr);
        log_softmax_kernel<<<B_DIM, 1024, 0, stream>>>(pred, fcpart);
        return;
    }

    // ---------------- fallback paths (smaller workspace) ----------------
    if (split)
        hipMemsetAsync(ws, 0, (size_t)163840 * 4, stream);
    else
        hipMemsetAsync(ws, 0, (size_t)1212416 * 4, stream);

    pack_misc_kernel<<<dim3(10, B_DIM), blk, 0, stream>>>(tok, embt, hidden, x0, x1);

    gemm2<2><<<dim3(8, 1, 2), blk, 0, stream>>>(
        hidden + (size_t)B_DIM * H_DIM, H_DIM, W2w, H_DIM, nullptr, 0, H_DIM,
        H_DIM, 512, proj, H_DIM, nullptr, 0, W2b, nullptr, nullptr, nullptr, nullptr);

    gemm2<1><<<dim3(8, 256, 1), blk, 0, stream>>>(
        enc, H_DIM, W1w, H_DIM, nullptr, 0, H_DIM,
        H_DIM, H_DIM, nullptr, 0, nullptr, 0, W1b, nullptr, proj, Vw, scores);
    softmax_context_kernel<float><<<dim3(B_DIM, 2), 256, 0, stream>>>(
        enc, scores, out_attn, x0, x2);

    if (split) {
        gemm2<3><<<dim3(32, 1, 4), blk, 0, stream>>>(
            x0, 2560, wih0, 1536, whh0, H_DIM, 1536, 2560, 640,
            gatesA, 4096, gAp, 524288, bih0, bhh0, nullptr, nullptr, nullptr);
        lstm_cell_kernel<<<dim3(4, B_DIM), blk, 0, stream>>>(
            gatesA, gAp, 3, 524288, cell, x1, 2048, out_hidden, out_cell);
    } else {
        gemm2<2><<<dim3(32, 1, 4), blk, 0, stream>>>(
            x0, 2560, wih0, 1536, whh0, H_DIM, 1536, 2560, 640,
            gatesA, 4096, nullptr, 0, bih0, bhh0, nullptr, nullptr, nullptr);
        lstm_cell_kernel<<<dim3(4, B_DIM), blk, 0, stream>>>(
            gatesA, nullptr, 0, 0, cell, x1, 2048, out_hidden, out_cell);
    }

    if (split) {
        gemm2<3><<<dim3(32, 1, 4), blk, 0, stream>>>(
            x1, 2048, wih1, H_DIM, whh1, H_DIM, H_DIM, 2048, 512,
            gatesB, 4096, gBp, 524288, bih1, bhh1, nullptr, nullptr, nullptr);
        lstm_cell_kernel<<<dim3(4, B_DIM), blk, 0, stream>>>(
            gatesB, gBp, 3, 524288, cell + (size_t)B_DIM * H_DIM, x2, 2048,
            out_hidden + (size_t)B_DIM * H_DIM, out_cell + (size_t)B_DIM * H_DIM);
    } else {
        gemm2<2><<<dim3(32, 1, 4), blk, 0, stream>>>(
            x1, 2048, wih1, H_DIM, whh1, H_DIM, H_DIM, 2048, 512,
            gatesB, 4096, nullptr, 0, bih1, bhh1, nullptr, nullptr, nullptr);
        lstm_cell_kernel<<<dim3(4, B_DIM), blk, 0, stream>>>(
            gatesB, nullptr, 0, 0, cell + (size_t)B_DIM * H_DIM, x2, 2048,
            out_hidden + (size_t)B_DIM * H_DIM, out_cell + (size_t)B_DIM * H_DIM);
    }

    if (split) {
        gemm2<3><<<dim3(250, 1, 2), blk, 0, stream>>>(
            x2, 2048, fcw, 2048, nullptr, 0, 2048, 2048, 1024,
            pred, V_DIM, fcpart, 4096000, fcb, nullptr, nullptr, nullptr, nullptr);
        log_softmax_kernel<<<B_DIM, 1024, 0, stream>>>(pred, fcpart);
    } else {
        gemm2<3><<<dim3(250, 1, 1), blk, 0, stream>>>(
            x2, 2048, fcw, 2048, nullptr, 0, 2048, 2048, 2048,
            pred, V_DIM, nullptr, 0, fcb, nullptr, nullptr, nullptr, nullptr);
        log_softmax_kernel<<<B_DIM, 1024, 0, stream>>>(pred, nullptr);
    }
}

// Round 3
// 752.351 us; speedup vs baseline: 1.2004x; 1.2004x over previous
//
#include <hip/hip_runtime.h>

#define H_DIM 1024
#define B_DIM 128
#define S_DIM 256
#define V_DIM 32000
#define E_DIM 512

typedef __bf16 bf16_t;
typedef bf16_t bf16x8 __attribute__((ext_vector_type(8)));
typedef bf16_t bf16x4 __attribute__((ext_vector_type(4)));
typedef float floatx4 __attribute__((ext_vector_type(4)));

#define BM 128
#define BN 128
#define BK 64
#define LDK (BK + 8)

__device__ inline float fast_tanh(float x) {
    x = fminf(fmaxf(x, -15.f), 15.f);
    float e = __expf(2.f * x);
    return (e - 1.f) / (e + 1.f);
}
__device__ inline float sigmoidf_(float x) { return 1.f / (1.f + __expf(-x)); }
__device__ inline bf16x4 cvt4(float4 v) {
    return (bf16x4){(bf16_t)v.x, (bf16_t)v.y, (bf16_t)v.z, (bf16_t)v.w};
}
__device__ __forceinline__ void gload16(const bf16_t* g, bf16_t* l) {
    __builtin_amdgcn_global_load_lds(
        (const __attribute__((address_space(1))) void*)g,
        (__attribute__((address_space(3))) void*)l, 16, 0, 0);
}

// ---------------- fused prep kernel (pathA) ----------------
// Pure BW-bound grid-stride float4 segments ONLY (no GEMV — that was the
// round-2 regression: 128 serial-GEMV blocks pinned the kernel at 245us/8% BW):
//   - zero scores                      (8192 f4)
//   - enc fp32 -> encbf bf16           (8388608 f4)
//   - W1  fp32 -> W1bf bf16            (262144 f4)
//   - x0[b][0..511]     = embt[tok[b]] (16384 f4)
//   - x0[b][1536..2559] = hidden[0][b] (32768 f4)
//   - x1[b][1024..2047] = hidden[1][b] (32768 f4)
__global__ __launch_bounds__(256) void prep_kernel(
    const float* __restrict__ enc, bf16_t* __restrict__ encbf,
    const float* __restrict__ W1w, bf16_t* __restrict__ W1bf,
    const int* __restrict__ tok, const float* __restrict__ embt,
    const float* __restrict__ hidden,
    float* __restrict__ x0, float* __restrict__ x1,
    float* __restrict__ scores)
{
    const int t = threadIdx.x;
    const long long N_ENC = 8388608, N_W1 = 262144, N_EMB = 16384,
                    N_H0 = 32768, N_H1 = 32768, N_SC = 8192;
    const long long total = N_ENC + N_W1 + N_EMB + N_H0 + N_H1 + N_SC;
    const long long stride = (long long)gridDim.x * 256;
    for (long long i = (long long)blockIdx.x * 256 + t; i < total; i += stride) {
        if (i < N_ENC) {
            float4 v = ((const float4*)enc)[i];
            ((bf16x4*)encbf)[i] = cvt4(v);
        } else if (i < N_ENC + N_W1) {
            long long k = i - N_ENC;
            ((bf16x4*)W1bf)[k] = cvt4(((const float4*)W1w)[k]);
        } else if (i < N_ENC + N_W1 + N_EMB) {
            long long k = i - N_ENC - N_W1;
            int b = (int)(k >> 7), j = (int)(k & 127);
            ((float4*)(x0 + (size_t)b * 2560))[j] =
                ((const float4*)(embt + (size_t)tok[b] * E_DIM))[j];
        } else if (i < N_ENC + N_W1 + N_EMB + N_H0) {
            long long k = i - N_ENC - N_W1 - N_EMB;
            int b = (int)(k >> 8), j = (int)(k & 255);
            ((float4*)(x0 + (size_t)b * 2560 + 1536))[j] =
                ((const float4*)(hidden + (size_t)b * H_DIM))[j];
        } else if (i < N_ENC + N_W1 + N_EMB + N_H0 + N_H1) {
            long long k = i - N_ENC - N_W1 - N_EMB - N_H0;
            int b = (int)(k >> 8), j = (int)(k & 255);
            ((float4*)(x1 + (size_t)b * 2048 + 1024))[j] =
                ((const float4*)(hidden + (size_t)B_DIM * H_DIM + (size_t)b * H_DIM))[j];
        } else {
            long long k = i - N_ENC - N_W1 - N_EMB - N_H0 - N_H1;
            ((float4*)scores)[k] = make_float4(0.f, 0.f, 0.f, 0.f);
        }
    }
}

// ---------------- bf16-input scores GEMM (Path A) ----------------
// scores[m] += sum_n tanh( (A@B^T)[m][n] + bias1[n] + proj[m>>8][n] ) * Vw[n]
// XCD-chunked bijective swizzle retained.
__global__ __launch_bounds__(256) void gemm_scores_bf16(
    const bf16_t* __restrict__ A, const bf16_t* __restrict__ B,
    const float* __restrict__ bias1, const float* __restrict__ proj,
    const float* __restrict__ Vw, float* __restrict__ scores)
{
    __shared__ bf16_t As[128 * 64];
    __shared__ bf16_t Bs[128 * 64];

    const int tid  = threadIdx.x;
    const int wid  = tid >> 6;
    const int lane = tid & 63;

    const int orig = blockIdx.y * gridDim.x + blockIdx.x;   // gridDim = (8,256)
    const int cpx  = (gridDim.x * gridDim.y) >> 3;
    const int wg   = (orig & 7) * cpx + (orig >> 3);
    const int m0 = (wg >> 3) * BM;
    const int n0 = (wg & 7) * BN;

    const int wave_m = (wid & 1) * 64;
    const int wave_n = (wid >> 1) * 64;
    const int laneM  = lane & 15;
    const int laneG  = lane >> 4;

    const int srow = lane >> 3;
    const int pc   = lane & 7;

    floatx4 acc[4][4];
#pragma unroll
    for (int i = 0; i < 4; i++)
#pragma unroll
        for (int j = 0; j < 4; j++) acc[i][j] = (floatx4)0.f;

    for (int k0 = 0; k0 < H_DIM; k0 += BK) {
#pragma unroll
        for (int i = 0; i < 4; i++) {
            int r  = wid * 32 + i * 8 + srow;
            int lc = pc ^ (r & 7);
            gload16(A + (size_t)(m0 + r) * H_DIM + k0 + lc * 8,
                    As + (wid * 32 + i * 8) * 64);
        }
#pragma unroll
        for (int i = 0; i < 4; i++) {
            int r  = wid * 32 + i * 8 + srow;
            int lc = pc ^ (r & 7);
            gload16(B + (size_t)(n0 + r) * H_DIM + k0 + lc * 8,
                    Bs + (wid * 32 + i * 8) * 64);
        }
        __syncthreads();

#pragma unroll
        for (int kk = 0; kk < 2; kk++) {
            bf16x8 af[4], bfb[4];
#pragma unroll
            for (int mt = 0; mt < 4; mt++) {
                int ra = wave_m + mt * 16 + laneM;
                int pa = (kk * 4 + laneG) ^ (ra & 7);
                af[mt] = *(const bf16x8*)(&As[ra * 64 + pa * 8]);
            }
#pragma unroll
            for (int nt = 0; nt < 4; nt++) {
                int rb = wave_n + nt * 16 + laneM;
                int pb = (kk * 4 + laneG) ^ (rb & 7);
                bfb[nt] = *(const bf16x8*)(&Bs[rb * 64 + pb * 8]);
            }
#pragma unroll
            for (int mt = 0; mt < 4; mt++)
#pragma unroll
                for (int nt = 0; nt < 4; nt++)
                    acc[mt][nt] = __builtin_amdgcn_mfma_f32_16x16x32_bf16(
                        af[mt], bfb[nt], acc[mt][nt], 0, 0, 0);
        }
        __syncthreads();
    }

#pragma unroll
    for (int mt = 0; mt < 4; mt++) {
#pragma unroll
        for (int r = 0; r < 4; r++) {
            int m = m0 + wave_m + mt * 16 + (lane >> 4) * 4 + r;
            int b = m >> 8;
            float v = 0.f;
#pragma unroll
            for (int nt = 0; nt < 4; nt++) {
                int n = n0 + wave_n + nt * 16 + laneM;
                float t = acc[mt][nt][r] + bias1[n] + proj[(size_t)b * H_DIM + n];
                v += fast_tanh(t) * Vw[n];
            }
#pragma unroll
            for (int off = 1; off < 16; off <<= 1) v += __shfl_xor(v, off, 64);
            if (laneM == 0) atomicAdd(&scores[m], v);
        }
    }
}

// ---------------- fp32-input GEMM with register-prefetch pipeline ----------------
template <int MODE>
__global__ __launch_bounds__(256) void gemm2(
    const float* __restrict__ A, int lda,
    const float* __restrict__ B1, int ldb1,
    const float* __restrict__ B2, int ldb2, int splitB,
    int K, int kChunk,
    float* __restrict__ C, int ldc,
    float* __restrict__ Cpart, long long partStride,
    const float* __restrict__ bias1, const float* __restrict__ bias2,
    const float* __restrict__ proj, const float* __restrict__ Vw,
    float* __restrict__ scores)
{
    __shared__ bf16_t As[BM][LDK];
    __shared__ bf16_t Bs[BN][LDK];

    const int tid  = threadIdx.x;
    const int wid  = tid >> 6;
    const int lane = tid & 63;

    int bx = blockIdx.x, by = blockIdx.y;
    if (MODE == 1) {
        int nwg  = gridDim.x * gridDim.y;
        int orig = by * gridDim.x + bx;
        int cpx  = nwg >> 3;
        int wg   = (orig & 7) * cpx + (orig >> 3);
        bx = wg % gridDim.x;
        by = wg / gridDim.x;
    }
    const int m0 = by * BM;
    const int n0 = bx * BN;

    const int wave_m = (wid & 1) * 64;
    const int wave_n = (wid >> 1) * 64;
    const int laneM  = lane & 15;
    const int laneK  = (lane >> 4) * 8;

    const int tk = (tid & 15) * 4;
    const int tr = tid >> 4;

    const int kStart = blockIdx.z * kChunk;
    const int kEnd   = min(K, kStart + kChunk);

    floatx4 acc[4][4];
#pragma unroll
    for (int i = 0; i < 4; i++)
#pragma unroll
        for (int j = 0; j < 4; j++) acc[i][j] = (floatx4)0.f;

    const float* Arow = A + (size_t)(m0 + tr) * lda + tk;

    float4 ar[8], br[8];
    auto loadA = [&](int k0) {
#pragma unroll
        for (int p = 0; p < 8; p++)
            ar[p] = *(const float4*)(Arow + (size_t)(p * 16) * lda + k0);
    };
    auto loadB = [&](int k0) {
        const float* Bp; size_t ldb; int kb;
        if (k0 < splitB) { Bp = B1; ldb = (size_t)ldb1; kb = k0 + tk; }
        else             { Bp = B2; ldb = (size_t)ldb2; kb = k0 - splitB + tk; }
        const float* Brow = Bp + (size_t)(n0 + tr) * ldb + kb;
#pragma unroll
        for (int p = 0; p < 8; p++)
            br[p] = *(const float4*)(Brow + (size_t)(p * 16) * ldb);
    };

    loadA(kStart); loadB(kStart);

    for (int k0 = kStart; k0 < kEnd; k0 += BK) {
#pragma unroll
        for (int p = 0; p < 8; p++) *(bf16x4*)(&As[tr + p * 16][tk]) = cvt4(ar[p]);
#pragma unroll
        for (int p = 0; p < 8; p++) *(bf16x4*)(&Bs[tr + p * 16][tk]) = cvt4(br[p]);
        __syncthreads();
        if (k0 + BK < kEnd) { loadA(k0 + BK); loadB(k0 + BK); }
#pragma unroll
        for (int kk = 0; kk < 2; kk++) {
            bf16x8 af[4], bfb[4];
#pragma unroll
            for (int mt = 0; mt < 4; mt++)
                af[mt] = *(const bf16x8*)(&As[wave_m + mt * 16 + laneM][kk * 32 + laneK]);
#pragma unroll
            for (int nt = 0; nt < 4; nt++)
                bfb[nt] = *(const bf16x8*)(&Bs[wave_n + nt * 16 + laneM][kk * 32 + laneK]);
#pragma unroll
            for (int mt = 0; mt < 4; mt++)
#pragma unroll
                for (int nt = 0; nt < 4; nt++)
                    acc[mt][nt] = __builtin_amdgcn_mfma_f32_16x16x32_bf16(
                        af[mt], bfb[nt], acc[mt][nt], 0, 0, 0);
        }
        __syncthreads();
    }

    if (MODE == 2 || MODE == 3) {
        const bool addb = (blockIdx.z == 0);
        float* dst = C;
        if (MODE == 3 && blockIdx.z > 0)
            dst = Cpart + (size_t)(blockIdx.z - 1) * partStride;
#pragma unroll
        for (int mt = 0; mt < 4; mt++) {
            int mrow = m0 + wave_m + mt * 16 + (lane >> 4) * 4;
#pragma unroll
            for (int nt = 0; nt < 4; nt++) {
                int n = n0 + wave_n + nt * 16 + laneM;
                float bsum = 0.f;
                if (addb) bsum = (bias1 ? bias1[n] : 0.f) + (bias2 ? bias2[n] : 0.f);
#pragma unroll
                for (int r = 0; r < 4; r++) {
                    float val = acc[mt][nt][r] + bsum;
                    if (MODE == 2) atomicAdd(&C[(size_t)(mrow + r) * ldc + n], val);
                    else           dst[(size_t)(mrow + r) * ldc + n] = val;
                }
            }
        }
    } else {  // MODE 1
#pragma unroll
        for (int mt = 0; mt < 4; mt++) {
#pragma unroll
            for (int r = 0; r < 4; r++) {
                int m = m0 + wave_m + mt * 16 + (lane >> 4) * 4 + r;
                int b = m >> 8;
                float v = 0.f;
#pragma unroll
                for (int nt = 0; nt < 4; nt++) {
                    int n = n0 + wave_n + nt * 16 + laneM;
                    float t = acc[mt][nt][r] + bias1[n] + proj[(size_t)b * H_DIM + n];
                    v += fast_tanh(t) * Vw[n];
                }
#pragma unroll
                for (int off = 1; off < 16; off <<= 1) v += __shfl_xor(v, off, 64);
                if (laneM == 0) atomicAdd(&scores[m], v);
            }
        }
    }
}

__global__ void convert_kernel(const float* __restrict__ src,
                               bf16_t* __restrict__ dst, int n4) {
    int i = blockIdx.x * blockDim.x + threadIdx.x;
    int stride = gridDim.x * blockDim.x;
    for (; i < n4; i += stride) {
        float4 v = ((const float4*)src)[i];
        ((bf16x4*)dst)[i] = cvt4(v);
    }
}

// fused softmax over scores + context reduce; grid (B, 2), 2 cols/thread
template <typename T>
__global__ __launch_bounds__(256) void softmax_context_kernel(
    const T* __restrict__ enc, const float* __restrict__ scores,
    float* __restrict__ out_attn, float* __restrict__ x0, float* __restrict__ x2)
{
    __shared__ float red[256];
    __shared__ float a_s[256];
    int b = blockIdx.x, t = threadIdx.x;
    int half = blockIdx.y;
    float v = scores[b * S_DIM + t];
    red[t] = v; __syncthreads();
    for (int off = 128; off > 0; off >>= 1) {
        if (t < off) red[t] = fmaxf(red[t], red[t + off]);
        __syncthreads();
    }
    float mx = red[0]; __syncthreads();
    float e = __expf(v - mx);
    red[t] = e; __syncthreads();
    for (int off = 128; off > 0; off >>= 1) {
        if (t < off) red[t] += red[t + off];
        __syncthreads();
    }
    float a = e / red[0];
    if (half == 0) out_attn[b * S_DIM + t] = a;
    a_s[t] = a;
    __syncthreads();

    const int col = half * 512 + 2 * t;
    const T* base = enc + (size_t)b * S_DIM * H_DIM + col;
    float c0 = 0.f, c1 = 0.f;
#pragma unroll 4
    for (int s = 0; s < S_DIM; s++) {
        float aw = a_s[s];
        const T* row = base + (size_t)s * H_DIM;
        c0 += aw * (float)row[0];
        c1 += aw * (float)row[1];
    }
    x0[(size_t)b * 2560 + 512 + col]      = c0;
    x0[(size_t)b * 2560 + 512 + col + 1]  = c1;
    x2[(size_t)b * 2048 + 1024 + col]     = c0;
    x2[(size_t)b * 2048 + 1024 + col + 1] = c1;
}

__global__ void pack_misc_kernel(const int* __restrict__ tok,
                                 const float* __restrict__ emb_table,
                                 const float* __restrict__ hidden,
                                 float* __restrict__ x0, float* __restrict__ x1) {
    int b = blockIdx.y;
    int k = blockIdx.x * 256 + threadIdx.x;
    if (k < E_DIM)
        x0[(size_t)b * 2560 + k] = emb_table[(size_t)tok[b] * E_DIM + k];
    else if (k < E_DIM + H_DIM)
        x0[(size_t)b * 2560 + 1024 + k] = hidden[b * H_DIM + (k - E_DIM)];
    else
        x1[(size_t)b * 2048 + 1024 + (k - E_DIM - H_DIM)] =
            hidden[(size_t)B_DIM * H_DIM + b * H_DIM + (k - E_DIM - H_DIM)];
}

__global__ void lstm_cell_kernel(const float* __restrict__ gates,
                                 const float* __restrict__ gpart, int nExtra,
                                 long long partStride,
                                 const float* __restrict__ c_in,
                                 float* __restrict__ hx, int hx_stride,
                                 float* __restrict__ h_out,
                                 float* __restrict__ c_out) {
    int b = blockIdx.y;
    int n = blockIdx.x * 256 + threadIdx.x;
    size_t base = (size_t)b * 4 * H_DIM;
    float gi = gates[base + n];
    float gf = gates[base + H_DIM + n];
    float gg = gates[base + 2 * H_DIM + n];
    float go = gates[base + 3 * H_DIM + n];
    for (int p = 0; p < nExtra; p++) {
        size_t pb = (size_t)p * partStride + base;
        gi += gpart[pb + n];
        gf += gpart[pb + H_DIM + n];
        gg += gpart[pb + 2 * H_DIM + n];
        go += gpart[pb + 3 * H_DIM + n];
    }
    float i = sigmoidf_(gi), f = sigmoidf_(gf), o = sigmoidf_(go);
    float g = fast_tanh(gg);
    float c = f * c_in[b * H_DIM + n] + i * g;
    float h = o * fast_tanh(c);
    hx[(size_t)b * hx_stride + n] = h;
    h_out[b * H_DIM + n] = h;
    c_out[b * H_DIM + n] = c;
}

__global__ __launch_bounds__(1024) void log_softmax_kernel(
    float* __restrict__ pred, const float* __restrict__ part) {
    __shared__ float red[1024];
    int b = blockIdx.x, t = threadIdx.x;
    float lv[32];
    float mx = -1e30f;
#pragma unroll
    for (int j = 0; j < 32; j++) {
        int v = t + j * 1024;
        float x = -1e30f;
        if (v < V_DIM) {
            x = pred[(size_t)b * V_DIM + v];
            if (part) x += part[(size_t)b * V_DIM + v];
        }
        lv[j] = x;
        mx = fmaxf(mx, x);
    }
    red[t] = mx; __syncthreads();
    for (int off = 512; off > 0; off >>= 1) {
        if (t < off) red[t] = fmaxf(red[t], red[t + off]);
        __syncthreads();
    }
    mx = red[0]; __syncthreads();
    float s = 0.f;
#pragma unroll
    for (int j = 0; j < 32; j++) s += __expf(lv[j] - mx);
    red[t] = s; __syncthreads();
    for (int off = 512; off > 0; off >>= 1) {
        if (t < off) red[t] += red[t + off];
        __syncthreads();
    }
    float lse = mx + __logf(red[0]);
#pragma unroll
    for (int j = 0; j < 32; j++) {
        int v = t + j * 1024;
        if (v < V_DIM) pred[(size_t)b * V_DIM + v] = lv[j] - lse;
    }
}

extern "C" void kernel_launch(void* const* d_in, const int* in_sizes, int n_in,
                              void* d_out, int out_size, void* d_ws, size_t ws_size,
                              hipStream_t stream) {
    const int*   tok    = (const int*)  d_in[0];
    const float* hidden = (const float*)d_in[1];
    const float* cell   = (const float*)d_in[2];
    const float* enc    = (const float*)d_in[3];
    const float* embt   = (const float*)d_in[4];
    const float* W1w    = (const float*)d_in[5];
    const float* W1b    = (const float*)d_in[6];
    const float* W2w    = (const float*)d_in[7];
    const float* W2b    = (const float*)d_in[8];
    const float* Vw     = (const float*)d_in[9];
    const float* wih0 = (const float*)d_in[11];
    const float* whh0 = (const float*)d_in[12];
    const float* bih0 = (const float*)d_in[13];
    const float* bhh0 = (const float*)d_in[14];
    const float* wih1 = (const float*)d_in[15];
    const float* whh1 = (const float*)d_in[16];
    const float* bih1 = (const float*)d_in[17];
    const float* bhh1 = (const float*)d_in[18];
    const float* fcw  = (const float*)d_in[19];
    const float* fcb  = (const float*)d_in[20];

    float* out        = (float*)d_out;
    float* pred       = out;
    float* out_hidden = out + (size_t)B_DIM * V_DIM;
    float* out_cell   = out_hidden + 2 * B_DIM * H_DIM;
    float* out_attn   = out_cell + 2 * B_DIM * H_DIM;

    // unified ws layout (float offsets)
    float* ws      = (float*)d_ws;
    float* scores  = ws;                      // 32768
    float* proj    = ws + 32768;              // 131072
    float* gatesA  = ws + 163840;             // 524288
    float* gatesB  = ws + 688128;             // 524288
    float* x0      = ws + 1212416;            // 327680
    float* x1      = ws + 1540096;            // 262144
    float* x2      = ws + 1802240;            // 262144
    float* gAp     = ws + 2064384;            // 3*524288   (fallback split path)
    float* gBp     = ws + 3637248;            // 3*524288
    float* fcpart  = ws + 5210112;            // 4096000 (also holds gates z-partials)
    bf16_t* encbf  = (bf16_t*)(ws + 9306112); // 33554432 bf16
    bf16_t* W1bf   = (bf16_t*)(ws + 26083328);// 1048576 bf16

    const bool pathA = ws_size >= (size_t)26607616 * 4;
    const bool pathB = !pathA && ws_size >= (size_t)9306112 * 4 + 16384000;
    const bool split = pathA || pathB;

    dim3 blk(256);

    if (pathA) {
        // proj = h_top @ W2^T + W2_b : single-chunk MFMA GEMM, direct store (no
        // zero-init, no atomics). 8 blocks, ~15us. (GEMV-in-prep was the r2 regression.)
        gemm2<3><<<dim3(8, 1, 1), blk, 0, stream>>>(
            hidden + (size_t)B_DIM * H_DIM, H_DIM, W2w, H_DIM, nullptr, 0, H_DIM,
            H_DIM, H_DIM, proj, H_DIM, nullptr, 0, W2b, nullptr,
            nullptr, nullptr, nullptr);

        // fused BW-bound prep: zero scores + enc/W1 convert + pack (1 dispatch)
        prep_kernel<<<dim3(2048), blk, 0, stream>>>(
            enc, encbf, W1w, W1bf, tok, embt, hidden, x0, x1, scores);

        gemm_scores_bf16<<<dim3(8, 256), blk, 0, stream>>>(
            encbf, W1bf, W1b, proj, Vw, scores);
        softmax_context_kernel<bf16_t><<<dim3(B_DIM, 2), 256, 0, stream>>>(
            encbf, scores, out_attn, x0, x2);

        // gates0 = x0 @ [wih0|whh0]^T + b  (M=128,N=4096,K=2560), z=8, partials in fcpart
        gemm2<3><<<dim3(32, 1, 8), blk, 0, stream>>>(
            x0, 2560, wih0, 1536, whh0, H_DIM, 1536, 2560, 320,
            gatesA, 4096, fcpart, 524288, bih0, bhh0, nullptr, nullptr, nullptr);
        lstm_cell_kernel<<<dim3(4, B_DIM), blk, 0, stream>>>(
            gatesA, fcpart, 7, 524288, cell, x1, 2048, out_hidden, out_cell);

        // gates1 = x1 @ [wih1|whh1]^T + b  (M=128,N=4096,K=2048), z=8
        gemm2<3><<<dim3(32, 1, 8), blk, 0, stream>>>(
            x1, 2048, wih1, H_DIM, whh1, H_DIM, H_DIM, 2048, 256,
            gatesB, 4096, fcpart, 524288, bih1, bhh1, nullptr, nullptr, nullptr);
        lstm_cell_kernel<<<dim3(4, B_DIM), blk, 0, stream>>>(
            gatesB, fcpart, 7, 524288, cell + (size_t)B_DIM * H_DIM, x2, 2048,
            out_hidden + (size_t)B_DIM * H_DIM, out_cell + (size_t)B_DIM * H_DIM);

        // logits = x2 @ fc_w^T + fc_b  (M=128,N=32000,K=2048), z=2
        gemm2<3><<<dim3(250, 1, 2), blk, 0, stream>>>(
            x2, 2048, fcw, 2048, nullptr, 0, 2048, 2048, 1024,
            pred, V_DIM, fcpart, 4096000, fcb, nullptr, nullptr, nullptr, nullptr);
        log_softmax_kernel<<<B_DIM, 1024, 0, stream>>>(pred, fcpart);
        return;
    }

    // ---------------- fallback paths (smaller workspace) ----------------
    if (split)
        hipMemsetAsync(ws, 0, (size_t)163840 * 4, stream);
    else
        hipMemsetAsync(ws, 0, (size_t)1212416 * 4, stream);

    pack_misc_kernel<<<dim3(10, B_DIM), blk, 0, stream>>>(tok, embt, hidden, x0, x1);

    gemm2<2><<<dim3(8, 1, 2), blk, 0, stream>>>(
        hidden + (size_t)B_DIM * H_DIM, H_DIM, W2w, H_DIM, nullptr, 0, H_DIM,
        H_DIM, 512, proj, H_DIM, nullptr, 0, W2b, nullptr, nullptr, nullptr, nullptr);

    gemm2<1><<<dim3(8, 256, 1), blk, 0, stream>>>(
        enc, H_DIM, W1w, H_DIM, nullptr, 0, H_DIM,
        H_DIM, H_DIM, nullptr, 0, nullptr, 0, W1b, nullptr, proj, Vw, scores);
    softmax_context_kernel<float><<<dim3(B_DIM, 2), 256, 0, stream>>>(
        enc, scores, out_attn, x0, x2);

    if (split) {
        gemm2<3><<<dim3(32, 1, 4), blk, 0, stream>>>(
            x0, 2560, wih0, 1536, whh0, H_DIM, 1536, 2560, 640,
            gatesA, 4096, gAp, 524288, bih0, bhh0, nullptr, nullptr, nullptr);
        lstm_cell_kernel<<<dim3(4, B_DIM), blk, 0, stream>>>(
            gatesA, gAp, 3, 524288, cell, x1, 2048, out_hidden, out_cell);
    } else {
        gemm2<2><<<dim3(32, 1, 4), blk, 0, stream>>>(
            x0, 2560, wih0, 1536, whh0, H_DIM, 1536, 2560, 640,
            gatesA, 4096, nullptr, 0, bih0, bhh0, nullptr, nullptr, nullptr);
        lstm_cell_kernel<<<dim3(4, B_DIM), blk, 0, stream>>>(
            gatesA, nullptr, 0, 0, cell, x1, 2048, out_hidden, out_cell);
    }

    if (split) {
        gemm2<3><<<dim3(32, 1, 4), blk, 0, stream>>>(
            x1, 2048, wih1, H_DIM, whh1, H_DIM, H_DIM, 2048, 512,
            gatesB, 4096, gBp, 524288, bih1, bhh1, nullptr, nullptr, nullptr);
        lstm_cell_kernel<<<dim3(4, B_DIM), blk, 0, stream>>>(
            gatesB, gBp, 3, 524288, cell + (size_t)B_DIM * H_DIM, x2, 2048,
            out_hidden + (size_t)B_DIM * H_DIM, out_cell + (size_t)B_DIM * H_DIM);
    } else {
        gemm2<2><<<dim3(32, 1, 4), blk, 0, stream>>>(
            x1, 2048, wih1, H_DIM, whh1, H_DIM, H_DIM, 2048, 512,
            gatesB, 4096, nullptr, 0, bih1, bhh1, nullptr, nullptr, nullptr);
        lstm_cell_kernel<<<dim3(4, B_DIM), blk, 0, stream>>>(
            gatesB, nullptr, 0, 0, cell + (size_t)B_DIM * H_DIM, x2, 2048,
            out_hidden + (size_t)B_DIM * H_DIM, out_cell + (size_t)B_DIM * H_DIM);
    }

    if (split) {
        gemm2<3><<<dim3(250, 1, 2), blk, 0, stream>>>(
            x2, 2048, fcw, 2048, nullptr, 0, 2048, 2048, 1024,
            pred, V_DIM, fcpart, 4096000, fcb, nullptr, nullptr, nullptr, nullptr);
        log_softmax_kernel<<<B_DIM, 1024, 0, stream>>>(pred, fcpart);
    } else {
        gemm2<3><<<dim3(250, 1, 1), blk, 0, stream>>>(
            x2, 2048, fcw, 2048, nullptr, 0, 2048, 2048, 2048,
            pred, V_DIM, nullptr, 0, fcb, nullptr, nullptr, nullptr, nullptr);
        log_softmax_kernel<<<B_DIM, 1024, 0, stream>>>(pred, nullptr);
    }
}

// Round 5
// 740.254 us; speedup vs baseline: 1.2201x; 1.0163x over previous
//
#include <hip/hip_runtime.h>

#define H_DIM 1024
#define B_DIM 128
#define S_DIM 256
#define V_DIM 32000
#define E_DIM 512

typedef __bf16 bf16_t;
typedef bf16_t bf16x8 __attribute__((ext_vector_type(8)));
typedef bf16_t bf16x4 __attribute__((ext_vector_type(4)));
typedef float floatx4 __attribute__((ext_vector_type(4)));

#define BM 128
#define BN 128
#define BK 64
#define LDK (BK + 8)

__device__ inline float fast_tanh(float x) {
    x = fminf(fmaxf(x, -15.f), 15.f);
    float e = __expf(2.f * x);
    return (e - 1.f) / (e + 1.f);
}
__device__ inline float sigmoidf_(float x) { return 1.f / (1.f + __expf(-x)); }
__device__ inline bf16x4 cvt4(float4 v) {
    return (bf16x4){(bf16_t)v.x, (bf16_t)v.y, (bf16_t)v.z, (bf16_t)v.w};
}
__device__ __forceinline__ void gload16(const bf16_t* g, bf16_t* l) {
    __builtin_amdgcn_global_load_lds(
        (const __attribute__((address_space(1))) void*)g,
        (__attribute__((address_space(3))) void*)l, 16, 0, 0);
}

// ---------------- fused prep kernel (pathA) ----------------
// Pure BW-bound grid-stride float4 segments ONLY:
//   zero scores, enc->bf16, W1->bf16, pack emb/hidden into x0/x1.
__global__ __launch_bounds__(256) void prep_kernel(
    const float* __restrict__ enc, bf16_t* __restrict__ encbf,
    const float* __restrict__ W1w, bf16_t* __restrict__ W1bf,
    const int* __restrict__ tok, const float* __restrict__ embt,
    const float* __restrict__ hidden,
    float* __restrict__ x0, float* __restrict__ x1,
    float* __restrict__ scores)
{
    const int t = threadIdx.x;
    const long long N_ENC = 8388608, N_W1 = 262144, N_EMB = 16384,
                    N_H0 = 32768, N_H1 = 32768, N_SC = 8192;
    const long long total = N_ENC + N_W1 + N_EMB + N_H0 + N_H1 + N_SC;
    const long long stride = (long long)gridDim.x * 256;
    for (long long i = (long long)blockIdx.x * 256 + t; i < total; i += stride) {
        if (i < N_ENC) {
            float4 v = ((const float4*)enc)[i];
            ((bf16x4*)encbf)[i] = cvt4(v);
        } else if (i < N_ENC + N_W1) {
            long long k = i - N_ENC;
            ((bf16x4*)W1bf)[k] = cvt4(((const float4*)W1w)[k]);
        } else if (i < N_ENC + N_W1 + N_EMB) {
            long long k = i - N_ENC - N_W1;
            int b = (int)(k >> 7), j = (int)(k & 127);
            ((float4*)(x0 + (size_t)b * 2560))[j] =
                ((const float4*)(embt + (size_t)tok[b] * E_DIM))[j];
        } else if (i < N_ENC + N_W1 + N_EMB + N_H0) {
            long long k = i - N_ENC - N_W1 - N_EMB;
            int b = (int)(k >> 8), j = (int)(k & 255);
            ((float4*)(x0 + (size_t)b * 2560 + 1536))[j] =
                ((const float4*)(hidden + (size_t)b * H_DIM))[j];
        } else if (i < N_ENC + N_W1 + N_EMB + N_H0 + N_H1) {
            long long k = i - N_ENC - N_W1 - N_EMB - N_H0;
            int b = (int)(k >> 8), j = (int)(k & 255);
            ((float4*)(x1 + (size_t)b * 2048 + 1024))[j] =
                ((const float4*)(hidden + (size_t)B_DIM * H_DIM + (size_t)b * H_DIM))[j];
        } else {
            long long k = i - N_ENC - N_W1 - N_EMB - N_H0 - N_H1;
            ((float4*)scores)[k] = make_float4(0.f, 0.f, 0.f, 0.f);
        }
    }
}

// ---------------- bf16-input scores GEMM (Path A) ----------------
// scores[m] += sum_n tanh( (A@B^T)[m][n] + bias1[n] + proj[m>>8][n] ) * Vw[n]
// XCD-chunked bijective swizzle retained.
__global__ __launch_bounds__(256) void gemm_scores_bf16(
    const bf16_t* __restrict__ A, const bf16_t* __restrict__ B,
    const float* __restrict__ bias1, const float* __restrict__ proj,
    const float* __restrict__ Vw, float* __restrict__ scores)
{
    __shared__ bf16_t As[128 * 64];
    __shared__ bf16_t Bs[128 * 64];

    const int tid  = threadIdx.x;
    const int wid  = tid >> 6;
    const int lane = tid & 63;

    const int orig = blockIdx.y * gridDim.x + blockIdx.x;   // gridDim = (8,256)
    const int cpx  = (gridDim.x * gridDim.y) >> 3;
    const int wg   = (orig & 7) * cpx + (orig >> 3);
    const int m0 = (wg >> 3) * BM;
    const int n0 = (wg & 7) * BN;

    const int wave_m = (wid & 1) * 64;
    const int wave_n = (wid >> 1) * 64;
    const int laneM  = lane & 15;
    const int laneG  = lane >> 4;

    const int srow = lane >> 3;
    const int pc   = lane & 7;

    floatx4 acc[4][4];
#pragma unroll
    for (int i = 0; i < 4; i++)
#pragma unroll
        for (int j = 0; j < 4; j++) acc[i][j] = (floatx4)0.f;

    for (int k0 = 0; k0 < H_DIM; k0 += BK) {
#pragma unroll
        for (int i = 0; i < 4; i++) {
            int r  = wid * 32 + i * 8 + srow;
            int lc = pc ^ (r & 7);
            gload16(A + (size_t)(m0 + r) * H_DIM + k0 + lc * 8,
                    As + (wid * 32 + i * 8) * 64);
        }
#pragma unroll
        for (int i = 0; i < 4; i++) {
            int r  = wid * 32 + i * 8 + srow;
            int lc = pc ^ (r & 7);
            gload16(B + (size_t)(n0 + r) * H_DIM + k0 + lc * 8,
                    Bs + (wid * 32 + i * 8) * 64);
        }
        __syncthreads();

#pragma unroll
        for (int kk = 0; kk < 2; kk++) {
            bf16x8 af[4], bfb[4];
#pragma unroll
            for (int mt = 0; mt < 4; mt++) {
                int ra = wave_m + mt * 16 + laneM;
                int pa = (kk * 4 + laneG) ^ (ra & 7);
                af[mt] = *(const bf16x8*)(&As[ra * 64 + pa * 8]);
            }
#pragma unroll
            for (int nt = 0; nt < 4; nt++) {
                int rb = wave_n + nt * 16 + laneM;
                int pb = (kk * 4 + laneG) ^ (rb & 7);
                bfb[nt] = *(const bf16x8*)(&Bs[rb * 64 + pb * 8]);
            }
#pragma unroll
            for (int mt = 0; mt < 4; mt++)
#pragma unroll
                for (int nt = 0; nt < 4; nt++)
                    acc[mt][nt] = __builtin_amdgcn_mfma_f32_16x16x32_bf16(
                        af[mt], bfb[nt], acc[mt][nt], 0, 0, 0);
        }
        __syncthreads();
    }

#pragma unroll
    for (int mt = 0; mt < 4; mt++) {
#pragma unroll
        for (int r = 0; r < 4; r++) {
            int m = m0 + wave_m + mt * 16 + (lane >> 4) * 4 + r;
            int b = m >> 8;
            float v = 0.f;
#pragma unroll
            for (int nt = 0; nt < 4; nt++) {
                int n = n0 + wave_n + nt * 16 + laneM;
                float t = acc[mt][nt][r] + bias1[n] + proj[(size_t)b * H_DIM + n];
                v += fast_tanh(t) * Vw[n];
            }
#pragma unroll
            for (int off = 1; off < 16; off <<= 1) v += __shfl_xor(v, off, 64);
            if (laneM == 0) atomicAdd(&scores[m], v);
        }
    }
}

// ---------------- fp32-input GEMM with register-prefetch pipeline ----------------
template <int MODE>
__global__ __launch_bounds__(256) void gemm2(
    const float* __restrict__ A, int lda,
    const float* __restrict__ B1, int ldb1,
    const float* __restrict__ B2, int ldb2, int splitB,
    int K, int kChunk,
    float* __restrict__ C, int ldc,
    float* __restrict__ Cpart, long long partStride,
    const float* __restrict__ bias1, const float* __restrict__ bias2,
    const float* __restrict__ proj, const float* __restrict__ Vw,
    float* __restrict__ scores)
{
    __shared__ bf16_t As[BM][LDK];
    __shared__ bf16_t Bs[BN][LDK];

    const int tid  = threadIdx.x;
    const int wid  = tid >> 6;
    const int lane = tid & 63;

    int bx = blockIdx.x, by = blockIdx.y;
    if (MODE == 1) {
        int nwg  = gridDim.x * gridDim.y;
        int orig = by * gridDim.x + bx;
        int cpx  = nwg >> 3;
        int wg   = (orig & 7) * cpx + (orig >> 3);
        bx = wg % gridDim.x;
        by = wg / gridDim.x;
    }
    const int m0 = by * BM;
    const int n0 = bx * BN;

    const int wave_m = (wid & 1) * 64;
    const int wave_n = (wid >> 1) * 64;
    const int laneM  = lane & 15;
    const int laneK  = (lane >> 4) * 8;

    const int tk = (tid & 15) * 4;
    const int tr = tid >> 4;

    const int kStart = blockIdx.z * kChunk;
    const int kEnd   = min(K, kStart + kChunk);

    floatx4 acc[4][4];
#pragma unroll
    for (int i = 0; i < 4; i++)
#pragma unroll
        for (int j = 0; j < 4; j++) acc[i][j] = (floatx4)0.f;

    const float* Arow = A + (size_t)(m0 + tr) * lda + tk;

    float4 ar[8], br[8];
    auto loadA = [&](int k0) {
#pragma unroll
        for (int p = 0; p < 8; p++)
            ar[p] = *(const float4*)(Arow + (size_t)(p * 16) * lda + k0);
    };
    auto loadB = [&](int k0) {
        const float* Bp; size_t ldb; int kb;
        if (k0 < splitB) { Bp = B1; ldb = (size_t)ldb1; kb = k0 + tk; }
        else             { Bp = B2; ldb = (size_t)ldb2; kb = k0 - splitB + tk; }
        const float* Brow = Bp + (size_t)(n0 + tr) * ldb + kb;
#pragma unroll
        for (int p = 0; p < 8; p++)
            br[p] = *(const float4*)(Brow + (size_t)(p * 16) * ldb);
    };

    loadA(kStart); loadB(kStart);

    for (int k0 = kStart; k0 < kEnd; k0 += BK) {
#pragma unroll
        for (int p = 0; p < 8; p++) *(bf16x4*)(&As[tr + p * 16][tk]) = cvt4(ar[p]);
#pragma unroll
        for (int p = 0; p < 8; p++) *(bf16x4*)(&Bs[tr + p * 16][tk]) = cvt4(br[p]);
        __syncthreads();
        if (k0 + BK < kEnd) { loadA(k0 + BK); loadB(k0 + BK); }
#pragma unroll
        for (int kk = 0; kk < 2; kk++) {
            bf16x8 af[4], bfb[4];
#pragma unroll
            for (int mt = 0; mt < 4; mt++)
                af[mt] = *(const bf16x8*)(&As[wave_m + mt * 16 + laneM][kk * 32 + laneK]);
#pragma unroll
            for (int nt = 0; nt < 4; nt++)
                bfb[nt] = *(const bf16x8*)(&Bs[wave_n + nt * 16 + laneM][kk * 32 + laneK]);
#pragma unroll
            for (int mt = 0; mt < 4; mt++)
#pragma unroll
                for (int nt = 0; nt < 4; nt++)
                    acc[mt][nt] = __builtin_amdgcn_mfma_f32_16x16x32_bf16(
                        af[mt], bfb[nt], acc[mt][nt], 0, 0, 0);
        }
        __syncthreads();
    }

    if (MODE == 2 || MODE == 3) {
        const bool addb = (blockIdx.z == 0);
        float* dst = C;
        if (MODE == 3 && blockIdx.z > 0)
            dst = Cpart + (size_t)(blockIdx.z - 1) * partStride;
#pragma unroll
        for (int mt = 0; mt < 4; mt++) {
            int mrow = m0 + wave_m + mt * 16 + (lane >> 4) * 4;
#pragma unroll
            for (int nt = 0; nt < 4; nt++) {
                int n = n0 + wave_n + nt * 16 + laneM;
                float bsum = 0.f;
                if (addb) bsum = (bias1 ? bias1[n] : 0.f) + (bias2 ? bias2[n] : 0.f);
#pragma unroll
                for (int r = 0; r < 4; r++) {
                    float val = acc[mt][nt][r] + bsum;
                    if (MODE == 2) atomicAdd(&C[(size_t)(mrow + r) * ldc + n], val);
                    else           dst[(size_t)(mrow + r) * ldc + n] = val;
                }
            }
        }
    } else {  // MODE 1
#pragma unroll
        for (int mt = 0; mt < 4; mt++) {
#pragma unroll
            for (int r = 0; r < 4; r++) {
                int m = m0 + wave_m + mt * 16 + (lane >> 4) * 4 + r;
                int b = m >> 8;
                float v = 0.f;
#pragma unroll
                for (int nt = 0; nt < 4; nt++) {
                    int n = n0 + wave_n + nt * 16 + laneM;
                    float t = acc[mt][nt][r] + bias1[n] + proj[(size_t)b * H_DIM + n];
                    v += fast_tanh(t) * Vw[n];
                }
#pragma unroll
                for (int off = 1; off < 16; off <<= 1) v += __shfl_xor(v, off, 64);
                if (laneM == 0) atomicAdd(&scores[m], v);
            }
        }
    }
}

__global__ void convert_kernel(const float* __restrict__ src,
                               bf16_t* __restrict__ dst, int n4) {
    int i = blockIdx.x * blockDim.x + threadIdx.x;
    int stride = gridDim.x * blockDim.x;
    for (; i < n4; i += stride) {
        float4 v = ((const float4*)src)[i];
        ((bf16x4*)dst)[i] = cvt4(v);
    }
}

// fused softmax over scores + context reduce.
// grid (B, 4): quarter q covers cols [q*256, q*256+256); 512 blocks -> 2/CU.
template <typename T>
__global__ __launch_bounds__(256) void softmax_context_kernel(
    const T* __restrict__ enc, const float* __restrict__ scores,
    float* __restrict__ out_attn, float* __restrict__ x0, float* __restrict__ x2)
{
    __shared__ float red[256];
    __shared__ float a_s[256];
    int b = blockIdx.x, t = threadIdx.x;
    int q = blockIdx.y;
    float v = scores[b * S_DIM + t];
    red[t] = v; __syncthreads();
    for (int off = 128; off > 0; off >>= 1) {
        if (t < off) red[t] = fmaxf(red[t], red[t + off]);
        __syncthreads();
    }
    float mx = red[0]; __syncthreads();
    float e = __expf(v - mx);
    red[t] = e; __syncthreads();
    for (int off = 128; off > 0; off >>= 1) {
        if (t < off) red[t] += red[t + off];
        __syncthreads();
    }
    float a = e / red[0];
    if (q == 0) out_attn[b * S_DIM + t] = a;
    a_s[t] = a;
    __syncthreads();

    const int col = q * 256 + t;
    const T* base = enc + (size_t)b * S_DIM * H_DIM + col;
    float c0 = 0.f;
#pragma unroll 4
    for (int s = 0; s < S_DIM; s++)
        c0 += a_s[s] * (float)base[(size_t)s * H_DIM];
    x0[(size_t)b * 2560 + 512 + col]  = c0;
    x2[(size_t)b * 2048 + 1024 + col] = c0;
}

__global__ void pack_misc_kernel(const int* __restrict__ tok,
                                 const float* __restrict__ emb_table,
                                 const float* __restrict__ hidden,
                                 float* __restrict__ x0, float* __restrict__ x1) {
    int b = blockIdx.y;
    int k = blockIdx.x * 256 + threadIdx.x;
    if (k < E_DIM)
        x0[(size_t)b * 2560 + k] = emb_table[(size_t)tok[b] * E_DIM + k];
    else if (k < E_DIM + H_DIM)
        x0[(size_t)b * 2560 + 1024 + k] = hidden[b * H_DIM + (k - E_DIM)];
    else
        x1[(size_t)b * 2048 + 1024 + (k - E_DIM - H_DIM)] =
            hidden[(size_t)B_DIM * H_DIM + b * H_DIM + (k - E_DIM - H_DIM)];
}

__global__ void lstm_cell_kernel(const float* __restrict__ gates,
                                 const float* __restrict__ gpart, int nExtra,
                                 long long partStride,
                                 const float* __restrict__ c_in,
                                 float* __restrict__ hx, int hx_stride,
                                 float* __restrict__ h_out,
                                 float* __restrict__ c_out) {
    int b = blockIdx.y;
    int n = blockIdx.x * 256 + threadIdx.x;
    size_t base = (size_t)b * 4 * H_DIM;
    float gi = gates[base + n];
    float gf = gates[base + H_DIM + n];
    float gg = gates[base + 2 * H_DIM + n];
    float go = gates[base + 3 * H_DIM + n];
    for (int p = 0; p < nExtra; p++) {
        size_t pb = (size_t)p * partStride + base;
        gi += gpart[pb + n];
        gf += gpart[pb + H_DIM + n];
        gg += gpart[pb + 2 * H_DIM + n];
        go += gpart[pb + 3 * H_DIM + n];
    }
    float i = sigmoidf_(gi), f = sigmoidf_(gf), o = sigmoidf_(go);
    float g = fast_tanh(gg);
    float c = f * c_in[b * H_DIM + n] + i * g;
    float h = o * fast_tanh(c);
    hx[(size_t)b * hx_stride + n] = h;
    h_out[b * H_DIM + n] = h;
    c_out[b * H_DIM + n] = c;
}

__global__ __launch_bounds__(1024) void log_softmax_kernel(
    float* __restrict__ pred, const float* __restrict__ part) {
    __shared__ float red[1024];
    int b = blockIdx.x, t = threadIdx.x;
    float lv[32];
    float mx = -1e30f;
#pragma unroll
    for (int j = 0; j < 32; j++) {
        int v = t + j * 1024;
        float x = -1e30f;
        if (v < V_DIM) {
            x = pred[(size_t)b * V_DIM + v];
            if (part) x += part[(size_t)b * V_DIM + v];
        }
        lv[j] = x;
        mx = fmaxf(mx, x);
    }
    red[t] = mx; __syncthreads();
    for (int off = 512; off > 0; off >>= 1) {
        if (t < off) red[t] = fmaxf(red[t], red[t + off]);
        __syncthreads();
    }
    mx = red[0]; __syncthreads();
    float s = 0.f;
#pragma unroll
    for (int j = 0; j < 32; j++) s += __expf(lv[j] - mx);
    red[t] = s; __syncthreads();
    for (int off = 512; off > 0; off >>= 1) {
        if (t < off) red[t] += red[t + off];
        __syncthreads();
    }
    float lse = mx + __logf(red[0]);
#pragma unroll
    for (int j = 0; j < 32; j++) {
        int v = t + j * 1024;
        if (v < V_DIM) pred[(size_t)b * V_DIM + v] = lv[j] - lse;
    }
}

extern "C" void kernel_launch(void* const* d_in, const int* in_sizes, int n_in,
                              void* d_out, int out_size, void* d_ws, size_t ws_size,
                              hipStream_t stream) {
    const int*   tok    = (const int*)  d_in[0];
    const float* hidden = (const float*)d_in[1];
    const float* cell   = (const float*)d_in[2];
    const float* enc    = (const float*)d_in[3];
    const float* embt   = (const float*)d_in[4];
    const float* W1w    = (const float*)d_in[5];
    const float* W1b    = (const float*)d_in[6];
    const float* W2w    = (const float*)d_in[7];
    const float* W2b    = (const float*)d_in[8];
    const float* Vw     = (const float*)d_in[9];
    const float* wih0 = (const float*)d_in[11];
    const float* whh0 = (const float*)d_in[12];
    const float* bih0 = (const float*)d_in[13];
    const float* bhh0 = (const float*)d_in[14];
    const float* wih1 = (const float*)d_in[15];
    const float* whh1 = (const float*)d_in[16];
    const float* bih1 = (const float*)d_in[17];
    const float* bhh1 = (const float*)d_in[18];
    const float* fcw  = (const float*)d_in[19];
    const float* fcb  = (const float*)d_in[20];

    float* out        = (float*)d_out;
    float* pred       = out;
    float* out_hidden = out + (size_t)B_DIM * V_DIM;
    float* out_cell   = out_hidden + 2 * B_DIM * H_DIM;
    float* out_attn   = out_cell + 2 * B_DIM * H_DIM;

    // unified ws layout (float offsets)
    float* ws      = (float*)d_ws;
    float* scores  = ws;                      // 32768
    float* proj    = ws + 32768;              // 131072
    float* gatesA  = ws + 163840;             // 524288
    float* gatesB  = ws + 688128;             // 524288
    float* x0      = ws + 1212416;            // 327680
    float* x1      = ws + 1540096;            // 262144
    float* x2      = ws + 1802240;            // 262144
    float* gAp     = ws + 2064384;            // 3*524288   (fallback split path)
    float* gBp     = ws + 3637248;            // 3*524288
    float* fcpart  = ws + 5210112;            // 4096000 (also holds gates z-partials)
    bf16_t* encbf  = (bf16_t*)(ws + 9306112); // 33554432 bf16
    bf16_t* W1bf   = (bf16_t*)(ws + 26083328);// 1048576 bf16

    const bool pathA = ws_size >= (size_t)26607616 * 4;
    const bool pathB = !pathA && ws_size >= (size_t)9306112 * 4 + 16384000;
    const bool split = pathA || pathB;

    dim3 blk(256);

    if (pathA) {
        // proj = h_top @ W2^T + W2_b : split-K z=4 (32 blocks) via atomics into
        // zeroed proj. (z=1's 8 blocks was latency-bound on 3% of the chip.)
        hipMemsetAsync(proj, 0, (size_t)131072 * 4, stream);
        gemm2<2><<<dim3(8, 1, 4), blk, 0, stream>>>(
            hidden + (size_t)B_DIM * H_DIM, H_DIM, W2w, H_DIM, nullptr, 0, H_DIM,
            H_DIM, 256, proj, H_DIM, nullptr, 0, W2b, nullptr,
            nullptr, nullptr, nullptr);

        // fused BW-bound prep: zero scores + enc/W1 convert + pack (1 dispatch)
        prep_kernel<<<dim3(2048), blk, 0, stream>>>(
            enc, encbf, W1w, W1bf, tok, embt, hidden, x0, x1, scores);

        gemm_scores_bf16<<<dim3(8, 256), blk, 0, stream>>>(
            encbf, W1bf, W1b, proj, Vw, scores);
        softmax_context_kernel<bf16_t><<<dim3(B_DIM, 4), 256, 0, stream>>>(
            encbf, scores, out_attn, x0, x2);

        // gates0 = x0 @ [wih0|whh0]^T + b  (M=128,N=4096,K=2560), z=8, partials in fcpart
        gemm2<3><<<dim3(32, 1, 8), blk, 0, stream>>>(
            x0, 2560, wih0, 1536, whh0, H_DIM, 1536, 2560, 320,
            gatesA, 4096, fcpart, 524288, bih0, bhh0, nullptr, nullptr, nullptr);
        lstm_cell_kernel<<<dim3(4, B_DIM), blk, 0, stream>>>(
            gatesA, fcpart, 7, 524288, cell, x1, 2048, out_hidden, out_cell);

        // gates1 = x1 @ [wih1|whh1]^T + b  (M=128,N=4096,K=2048), z=8
        gemm2<3><<<dim3(32, 1, 8), blk, 0, stream>>>(
            x1, 2048, wih1, H_DIM, whh1, H_DIM, H_DIM, 2048, 256,
            gatesB, 4096, fcpart, 524288, bih1, bhh1, nullptr, nullptr, nullptr);
        lstm_cell_kernel<<<dim3(4, B_DIM), blk, 0, stream>>>(
            gatesB, fcpart, 7, 524288, cell + (size_t)B_DIM * H_DIM, x2, 2048,
            out_hidden + (size_t)B_DIM * H_DIM, out_cell + (size_t)B_DIM * H_DIM);

        // logits = x2 @ fc_w^T + fc_b  (M=128,N=32000,K=2048), z=2
        gemm2<3><<<dim3(250, 1, 2), blk, 0, stream>>>(
            x2, 2048, fcw, 2048, nullptr, 0, 2048, 2048, 1024,
            pred, V_DIM, fcpart, 4096000, fcb, nullptr, nullptr, nullptr, nullptr);
        log_softmax_kernel<<<B_DIM, 1024, 0, stream>>>(pred, fcpart);
        return;
    }

    // ---------------- fallback paths (smaller workspace) ----------------
    if (split)
        hipMemsetAsync(ws, 0, (size_t)163840 * 4, stream);
    else
        hipMemsetAsync(ws, 0, (size_t)1212416 * 4, stream);

    pack_misc_kernel<<<dim3(10, B_DIM), blk, 0, stream>>>(tok, embt, hidden, x0, x1);

    gemm2<2><<<dim3(8, 1, 2), blk, 0, stream>>>(
        hidden + (size_t)B_DIM * H_DIM, H_DIM, W2w, H_DIM, nullptr, 0, H_DIM,
        H_DIM, 512, proj, H_DIM, nullptr, 0, W2b, nullptr, nullptr, nullptr, nullptr);

    gemm2<1><<<dim3(8, 256, 1), blk, 0, stream>>>(
        enc, H_DIM, W1w, H_DIM, nullptr, 0, H_DIM,
        H_DIM, H_DIM, nullptr, 0, nullptr, 0, W1b, nullptr, proj, Vw, scores);
    softmax_context_kernel<float><<<dim3(B_DIM, 4), 256, 0, stream>>>(
        enc, scores, out_attn, x0, x2);

    if (split) {
        gemm2<3><<<dim3(32, 1, 4), blk, 0, stream>>>(
            x0, 2560, wih0, 1536, whh0, H_DIM, 1536, 2560, 640,
            gatesA, 4096, gAp, 524288, bih0, bhh0, nullptr, nullptr, nullptr);
        lstm_cell_kernel<<<dim3(4, B_DIM), blk, 0, stream>>>(
            gatesA, gAp, 3, 524288, cell, x1, 2048, out_hidden, out_cell);
    } else {
        gemm2<2><<<dim3(32, 1, 4), blk, 0, stream>>>(
            x0, 2560, wih0, 1536, whh0, H_DIM, 1536, 2560, 640,
            gatesA, 4096, nullptr, 0, bih0, bhh0, nullptr, nullptr, nullptr);
        lstm_cell_kernel<<<dim3(4, B_DIM), blk, 0, stream>>>(
            gatesA, nullptr, 0, 0, cell, x1, 2048, out_hidden, out_cell);
    }

    if (split) {
        gemm2<3><<<dim3(32, 1, 4), blk, 0, stream>>>(
            x1, 2048, wih1, H_DIM, whh1, H_DIM, H_DIM, 2048, 512,
            gatesB, 4096, gBp, 524288, bih1, bhh1, nullptr, nullptr, nullptr);
        lstm_cell_kernel<<<dim3(4, B_DIM), blk, 0, stream>>>(
            gatesB, gBp, 3, 524288, cell + (size_t)B_DIM * H_DIM, x2, 2048,
            out_hidden + (size_t)B_DIM * H_DIM, out_cell + (size_t)B_DIM * H_DIM);
    } else {
        gemm2<2><<<dim3(32, 1, 4), blk, 0, stream>>>(
            x1, 2048, wih1, H_DIM, whh1, H_DIM, H_DIM, 2048, 512,
            gatesB, 4096, nullptr, 0, bih1, bhh1, nullptr, nullptr, nullptr);
        lstm_cell_kernel<<<dim3(4, B_DIM), blk, 0, stream>>>(
            gatesB, nullptr, 0, 0, cell + (size_t)B_DIM * H_DIM, x2, 2048,
            out_hidden + (size_t)B_DIM * H_DIM, out_cell + (size_t)B_DIM * H_DIM);
    }

    if (split) {
        gemm2<3><<<dim3(250, 1, 2), blk, 0, stream>>>(
            x2, 2048, fcw, 2048, nullptr, 0, 2048, 2048, 1024,
            pred, V_DIM, fcpart, 4096000, fcb, nullptr, nullptr, nullptr, nullptr);
        log_softmax_kernel<<<B_DIM, 1024, 0, stream>>>(pred, fcpart);
    } else {
        gemm2<3><<<dim3(250, 1, 1), blk, 0, stream>>>(
            x2, 2048, fcw, 2048, nullptr, 0, 2048, 2048, 2048,
            pred, V_DIM, nullptr, 0, fcb, nullptr, nullptr, nullptr, nullptr);
        log_softmax_kernel<<<B_DIM, 1024, 0, stream>>>(pred, nullptr);
    }
}